// Round 6
// baseline (619.138 us; speedup 1.0000x reference)
//
#include <hip/hip_runtime.h>
#include <hip/hip_bf16.h>
#include <math.h>

// ---------- types ----------
typedef short short8 __attribute__((ext_vector_type(8)));
typedef float f32x4 __attribute__((ext_vector_type(4)));

#define MFMA16(a, b, c) __builtin_amdgcn_mfma_f32_16x16x32_bf16((a), (b), (c), 0, 0, 0)
#define NEGBIG (-1e30f)
#define SM2 0.18033688f   // 0.125 * log2(e): QK^T softmax done in exp2 domain

// raw barrier + compiler fence (counted-vmcnt pipeline: loads stay in flight across it)
#define BARRIER() { __builtin_amdgcn_sched_barrier(0); \
                    asm volatile("s_barrier" ::: "memory"); \
                    __builtin_amdgcn_sched_barrier(0); }
#define WAITVM(n) asm volatile("s_waitcnt vmcnt(" #n ")" ::: "memory")

__device__ __forceinline__ unsigned short f2bf(float f) {
  unsigned u = __builtin_bit_cast(unsigned, f);
  u += 0x7FFFu + ((u >> 16) & 1u);   // RNE
  return (unsigned short)(u >> 16);
}
__device__ __forceinline__ float b2f(unsigned short h) {
  return __builtin_bit_cast(float, (unsigned)h << 16);
}
__device__ __forceinline__ unsigned cvtpk(float lo, float hi) {
  unsigned r;
  asm("v_cvt_pk_bf16_f32 %0, %1, %2" : "=v"(r) : "v"(lo), "v"(hi));
  return r;
}
// async global->LDS, 16B/lane; LDS dest = wave-uniform base (+ lane*16 by HW)
__device__ __forceinline__ void gload16(const void* g, void* l) {
  __builtin_amdgcn_global_load_lds((const __attribute__((address_space(1))) unsigned*)g,
                                   (__attribute__((address_space(3))) unsigned*)l, 16, 0, 0);
}

// ---------- small kernels ----------
__global__ __launch_bounds__(256) void cast_f32_bf16(const float* __restrict__ in,
                                                     unsigned short* __restrict__ out,
                                                     long n) {
  long i = ((long)blockIdx.x * 256 + threadIdx.x) * 4;
  if (i + 3 < n) {
    float4 v = *(const float4*)(in + i);
    ushort4 o;
    o.x = f2bf(v.x); o.y = f2bf(v.y); o.z = f2bf(v.z); o.w = f2bf(v.w);
    *(ushort4*)(out + i) = o;
  }
}

// merged transpose of the 5 weight matrices [512,N] fp32 -> [N,512] bf16 (contiguous dst)
__global__ __launch_bounds__(256) void wtrans5(const float* __restrict__ w0,
                                               const float* __restrict__ w1,
                                               const float* __restrict__ w2,
                                               const float* __restrict__ w3,
                                               const float* __restrict__ w4,
                                               unsigned short* __restrict__ dst) {
  int seg = blockIdx.y;
  const float* src; int N; long doff;
  switch (seg) {
    case 0:  src = w0; N = 768; doff = 0;       break;   // gqkv -> wtg
    case 1:  src = w1; N = 256; doff = 393216;  break;   // pq   -> wtq
    case 2:  src = w2; N = 512; doff = 524288;  break;   // pkv  -> wtkv
    case 3:  src = w3; N = 512; doff = 786432;  break;   // conv -> wtc
    default: src = w4; N = 512; doff = 1048576; break;   // proj -> wtp
  }
  int idx = blockIdx.x * 256 + threadIdx.x;
  if (idx < 512 * N) {
    int k = idx / N, n = idx - k * N;
    dst[doff + (long)n * 512 + k] = f2bf(src[idx]);
  }
}

// pooled[b,j,c] = mean_w xbf[b, j*5+w, c]  (bf16 in, bf16 out)
__global__ __launch_bounds__(256) void pool_mean(const unsigned short* __restrict__ x,
                                                 unsigned short* __restrict__ pr) {
  long bi = blockIdx.x;                 // b*800 + j
  const unsigned short* src = x + bi * 2560;
  int c = threadIdx.x * 2;
  float ax = 0.f, ay = 0.f;
#pragma unroll
  for (int w = 0; w < 5; ++w) {
    unsigned v = *(const unsigned*)(src + w * 512 + c);
    ax += b2f((unsigned short)(v & 0xffff));
    ay += b2f((unsigned short)(v >> 16));
  }
  unsigned out = (unsigned)f2bf(ax * 0.2f) | ((unsigned)f2bf(ay * 0.2f) << 16);
  *(unsigned*)(pr + bi * 512 + c) = out;
}

// LayerNorm (eps 1e-5, biased var) + erf-GELU ; fp32 [rows,512] -> bf16
__global__ __launch_bounds__(256) void ln_gelu(const float* __restrict__ in,
                                               const float* __restrict__ g,
                                               const float* __restrict__ be,
                                               unsigned short* __restrict__ out) {
  long row = blockIdx.x;
  const float* src = in + row * 512;
  int tid = threadIdx.x;
  float2 v = *(const float2*)(src + tid * 2);
  float s = v.x + v.y, sq = v.x * v.x + v.y * v.y;
#pragma unroll
  for (int m = 1; m < 64; m <<= 1) {
    s  += __shfl_xor(s, m);
    sq += __shfl_xor(sq, m);
  }
  __shared__ float ss[4], ssq[4];
  int wv = tid >> 6;
  if ((tid & 63) == 0) { ss[wv] = s; ssq[wv] = sq; }
  __syncthreads();
  s  = ss[0] + ss[1] + ss[2] + ss[3];
  sq = ssq[0] + ssq[1] + ssq[2] + ssq[3];
  float mu = s * (1.0f / 512.0f);
  float var = sq * (1.0f / 512.0f) - mu * mu;
  float rs = rsqrtf(var + 1e-5f);
  int c = tid * 2;
#pragma unroll
  for (int e = 0; e < 2; ++e) {
    float xv = (e == 0 ? v.x : v.y);
    float y = (xv - mu) * rs * g[c + e] + be[c + e];
    float ge = 0.5f * y * (1.0f + erff(y * 0.70710678118654752f));
    out[row * 512 + c + e] = f2bf(ge);
  }
}

// ---------- V transpose: src [seq][800][64] -> dst [seq][64][800] ----------
__global__ __launch_bounds__(256) void vtrans(const unsigned short* __restrict__ src,
                                              unsigned short* __restrict__ dst) {
  __shared__ unsigned short tile[64][64];
  int jt = blockIdx.x, s = blockIdx.y;
  int tid = threadIdx.x;
#pragma unroll
  for (int p = 0; p < 2; ++p) {
    int idx = p * 256 + tid;
    int j = idx >> 3, d8 = (idx & 7) * 8;
    int jg = min(jt * 64 + j, 799);
    short8 v = *(const short8*)(src + ((long)s * 800 + jg) * 64 + d8);
    *(short8*)&tile[j][d8] = v;
  }
  __syncthreads();
  int d = tid >> 2, jseg = (tid & 3) * 16;
  if (jt * 64 + jseg < 800) {
    short8 h0, h1;
#pragma unroll
    for (int i = 0; i < 8; ++i) { h0[i] = (short)tile[jseg + i][d]; h1[i] = (short)tile[jseg + 8 + i][d]; }
    unsigned short* o = dst + ((long)s * 64 + d) * 800 + jt * 64 + jseg;
    *(short8*)o = h0;
    *(short8*)(o + 8) = h1;
  }
}

// ---------- small GEMM (pool branch): 128x128 tile, 4 waves, BK=32 ----------
// gmode 1: fp32 out0 [M][N];  gmode 3: kv-split gathered K/V [64][800][64]
__global__ __launch_bounds__(256) void gemm_bf16(const unsigned short* __restrict__ A,
                                                 const unsigned short* __restrict__ Bt,
                                                 const float* __restrict__ bias,
                                                 void* __restrict__ out0, void* __restrict__ out1,
                                                 int M, int N, int K, int gmode) {
  __shared__ unsigned short lA[2][128 * 32];
  __shared__ unsigned short lB[2][128 * 32];
  const int tid = threadIdx.x;
  const int lane = tid & 63, wv = tid >> 6;
  const int wr = wv >> 1, wc = wv & 1;
  const int l15 = lane & 15, lg = lane >> 4;

  const int nwg = gridDim.x * gridDim.y;
  const int bid = blockIdx.y * gridDim.x + blockIdx.x;
  const int w = (bid & 7) * (nwg >> 3) + (bid >> 3);
  const int m0 = (w / gridDim.x) * 128, n0 = (w % gridDim.x) * 128;

  const int r0  = tid >> 2;
  const int sw0 = ((tid & 3) * 16) ^ ((r0 & 3) << 4);
  const unsigned short* As0 = A  + (size_t)(m0 + r0)      * K + (sw0 >> 1);
  const unsigned short* As1 = A  + (size_t)(m0 + 64 + r0) * K + (sw0 >> 1);
  const unsigned short* Bs0 = Bt + (size_t)(n0 + r0)      * K + (sw0 >> 1);
  const unsigned short* Bs1 = Bt + (size_t)(n0 + 64 + r0) * K + (sw0 >> 1);

  f32x4 acc[4][4] = {};

#define GSTAGE(buf, k0)                                   \
  {                                                       \
    gload16(As0 + (k0), &lA[buf][wv * 512]);              \
    gload16(As1 + (k0), &lA[buf][2048 + wv * 512]);       \
    gload16(Bs0 + (k0), &lB[buf][wv * 512]);              \
    gload16(Bs1 + (k0), &lB[buf][2048 + wv * 512]);       \
  }

  const int nt = K >> 5;
  GSTAGE(0, 0);
  if (nt > 1) GSTAGE(1, 32);
  for (int t = 0; t < nt; ++t) {
    if (t + 1 < nt) { WAITVM(4); } else { WAITVM(0); }
    BARRIER();
    short8 af[4], bfr[4];
#pragma unroll
    for (int s2 = 0; s2 < 4; ++s2) {
      int ra = wr * 64 + s2 * 16 + l15;
      int rb = wc * 64 + s2 * 16 + l15;
      af[s2]  = *(const short8*)((char*)lA[t & 1] + ra * 64 + ((lg * 16) ^ ((ra & 3) << 4)));
      bfr[s2] = *(const short8*)((char*)lB[t & 1] + rb * 64 + ((lg * 16) ^ ((rb & 3) << 4)));
    }
#pragma unroll
    for (int i = 0; i < 4; ++i)
#pragma unroll
      for (int j = 0; j < 4; ++j)
        acc[i][j] = MFMA16(af[i], bfr[j], acc[i][j]);
    BARRIER();
    if (t + 2 < nt) GSTAGE(t & 1, (t + 2) * 32);
  }
#undef GSTAGE

#pragma unroll
  for (int i = 0; i < 4; ++i) {
#pragma unroll
    for (int r = 0; r < 4; ++r) {
      int row = m0 + wr * 64 + i * 16 + lg * 4 + r;
      long rg = 0;
      if (gmode == 3) {
        int b = row / 800, jj = row - b * 800;
        rg = (long)b * 204800 + (long)jj * 64;
      }
#pragma unroll
      for (int j = 0; j < 4; ++j) {
        int col = n0 + wc * 64 + j * 16 + l15;
        float vv = acc[i][j][r] + bias[col];
        if (gmode == 1) {
          ((float*)out0)[(size_t)row * N + col] = vv;
        } else {  // gmode 3
          int hh = (col >> 6) & 3, d = col & 63;
          unsigned short* dst = (col < 256) ? (unsigned short*)out0 : (unsigned short*)out1;
          dst[rg + hh * 51200 + d] = f2bf(vv);
        }
      }
    }
  }
}

// ---------- big GEMM: 256x256 tile, 8 waves (2Mx4N), wave-tile 128x64, BK=64 ----------
// 128KB LDS dbuf, counted vmcnt (8 loads/stage), conflict-free 8-row XOR swizzle.
// gmode 1: fp32 out0 [M][N]
// gmode 2: merged qkv+poolq (N=1024): out0=Qg*SM2, out1=Kg, out2=Vg, out3=Qp*SM2
__global__ __launch_bounds__(512, 2) void gemm256(const unsigned short* __restrict__ A,
                                                  const unsigned short* __restrict__ Bt,
                                                  const float* __restrict__ bias,
                                                  const float* __restrict__ bias2,
                                                  void* __restrict__ out0, void* __restrict__ out1,
                                                  void* __restrict__ out2, void* __restrict__ out3,
                                                  int M, int N, int K, int gmode) {
  __shared__ unsigned short lA[2][256 * 64];   // 32KB per buf
  __shared__ unsigned short lB[2][256 * 64];   // total 128KB
  const int tid = threadIdx.x;
  const int lane = tid & 63, wv = tid >> 6;    // 8 waves
  const int wr = wv >> 2, wc = wv & 3;         // 2M x 4N
  const int l15 = lane & 15, lg = lane >> 4;

  // bijective XCD swizzle (m204)
  const int nwg = gridDim.x * gridDim.y;
  const int bid = blockIdx.y * gridDim.x + blockIdx.x;
  const int q = nwg >> 3, r8 = nwg & 7;
  const int xcd = bid & 7, idx = bid >> 3;
  const int w = (xcd < r8 ? xcd * (q + 1) : r8 * (q + 1) + (xcd - r8) * q) + idx;
  const int m0 = (w / gridDim.x) * 256, n0 = (w % gridDim.x) * 256;

  // staging: 8 gload16/thread/K-step. group g covers 64 rows (8KB of the 32KB tile).
  // thread -> row = g*64 + (tid>>3); source col pre-swizzled so LDS stays linear.
  const int srow = tid >> 3;                                        // 0..63
  const int scol = ((((lane & 7) ^ (lane >> 3)) << 4)) >> 1;        // element offset
  const unsigned short* Ag[4];
  const unsigned short* Bg[4];
#pragma unroll
  for (int g = 0; g < 4; ++g) {
    Ag[g] = A  + (size_t)(m0 + g * 64 + srow) * K + scol;
    Bg[g] = Bt + (size_t)(n0 + g * 64 + srow) * K + scol;
  }

  f32x4 acc[8][4] = {};

#define GSTAGE2(buf, k0)                                            \
  {                                                                 \
    _Pragma("unroll")                                               \
    for (int g = 0; g < 4; ++g)                                     \
      gload16(Ag[g] + (k0), &lA[buf][g * 4096 + wv * 512]);         \
    _Pragma("unroll")                                               \
    for (int g = 0; g < 4; ++g)                                     \
      gload16(Bg[g] + (k0), &lB[buf][g * 4096 + wv * 512]);         \
  }

  const int nt = K >> 6;                       // BK=64
  GSTAGE2(0, 0);
  if (nt > 1) GSTAGE2(1, 64);
  for (int t = 0; t < nt; ++t) {
    if (t + 1 < nt) { WAITVM(8); } else { WAITVM(0); }
    BARRIER();
#pragma unroll
    for (int kk = 0; kk < 2; ++kk) {
      short8 af[8], bf[4];
#pragma unroll
      for (int i = 0; i < 8; ++i) {
        int ra = wr * 128 + i * 16 + l15;
        af[i] = *(const short8*)((char*)lA[t & 1] + ra * 128 +
                                 ((kk * 64 + lg * 16) ^ ((ra & 7) << 4)));
      }
#pragma unroll
      for (int j = 0; j < 4; ++j) {
        int rb = wc * 64 + j * 16 + l15;
        bf[j] = *(const short8*)((char*)lB[t & 1] + rb * 128 +
                                 ((kk * 64 + lg * 16) ^ ((rb & 7) << 4)));
      }
      __builtin_amdgcn_s_setprio(1);
#pragma unroll
      for (int i = 0; i < 8; ++i)
#pragma unroll
        for (int j = 0; j < 4; ++j)
          acc[i][j] = MFMA16(af[i], bf[j], acc[i][j]);
      __builtin_amdgcn_s_setprio(0);
    }
    BARRIER();
    if (t + 2 < nt) GSTAGE2(t & 1, (t + 2) * 64);
  }
#undef GSTAGE2

  // ---- epilogue ----
#pragma unroll
  for (int i = 0; i < 8; ++i) {
#pragma unroll
    for (int rr = 0; rr < 4; ++rr) {
      int row = m0 + wr * 128 + i * 16 + lg * 4 + rr;
      long rg = 0, rq = 0;
      if (gmode == 2) {
        int b = row / 4000, l = row - b * 4000;
        int jj = l / 5, ww = l - jj * 5;
        rg = (long)(b * 5 + ww) * 204800 + (long)jj * 64;
        rq = (long)row * 256;
      }
#pragma unroll
      for (int j = 0; j < 4; ++j) {
        int col = n0 + wc * 64 + j * 16 + l15;
        float vv = acc[i][j][rr];
        if (gmode == 1) {
          ((float*)out0)[(size_t)row * N + col] = vv + bias[col];
        } else {  // gmode 2
          vv += (col < 768) ? bias[col] : bias2[col - 768];
          int sec = col >> 8;
          if (sec == 3) {
            ((unsigned short*)out3)[rq + (col - 768)] = f2bf(vv * SM2);
          } else {
            int hh = (col >> 6) & 3, d = col & 63;
            unsigned short* dst = (sec == 0) ? (unsigned short*)out0
                                 : (sec == 1) ? (unsigned short*)out1 : (unsigned short*)out2;
            dst[rg + hh * 51200 + d] = f2bf(sec == 0 ? vv * SM2 : vv);
          }
        }
      }
    }
  }
}

// ---------- flash attention v4: counted-vmcnt dbuf pipeline ----------
__global__ __launch_bounds__(256) void flash_v4(const unsigned short* __restrict__ qsrc,
                                                const unsigned short* __restrict__ ksrc,
                                                const unsigned short* __restrict__ vsrc,
                                                unsigned short* __restrict__ cat,
                                                int mode) {
  __shared__ unsigned short lK[2][64 * 64];   // [tok][d] swizzled (byte ^= (tok&7)<<4)
  __shared__ unsigned short lV[2][64 * 64];   // [d][tok] swizzled
  __shared__ unsigned short lP[4][16 * 64];   // per-wave [q16][tok64] swizzled

  const int tid = threadIdx.x, lane = tid & 63, wv = tid >> 6;
  const int l15 = lane & 15, lg = lane >> 4;

  const int nwg = gridDim.x * gridDim.y;
  const int bid = blockIdx.y * gridDim.x + blockIdx.x;
  const int w = (bid & 7) * (nwg >> 3) + (bid >> 3);
  const int qt = w % gridDim.x, sidx = w / gridDim.x;
  const int nk = 800;

  const unsigned short* Kb = ksrc + (long)sidx * 800 * 64;
  const unsigned short* Vb = vsrc + (long)sidx * 64 * 800;
  const unsigned short* Qb;
  unsigned short* Ob;
  long qstr, ostr;
  int nq;
  if (mode == 0) {
    int b = sidx / 20, rem = sidx % 20, ww = rem >> 2, h = rem & 3;
    Qb = qsrc + (long)sidx * 800 * 64; qstr = 64;
    Ob = cat + ((long)b * 4000 + ww) * 512 + h * 64; ostr = 2560;
    nq = 800;
  } else {
    int b = sidx >> 2, h = sidx & 3;
    Qb = qsrc + (long)b * 4000 * 256 + h * 64; qstr = 256;
    Ob = cat + (long)b * 4000 * 512 + 256 + h * 64; ostr = 512;
    nq = 4000;
  }

  int qrow = qt * 64 + wv * 16 + l15;
  int qrc = min(qrow, nq - 1);
  short8 q0 = *(const short8*)(Qb + (long)qrc * qstr + lg * 8);
  short8 q1 = *(const short8*)(Qb + (long)qrc * qstr + 32 + lg * 8);

  float m = NEGBIG, ls = 0.f;
  f32x4 oacc[4] = {};

  const int rowp = tid >> 3;
  const int swb  = ((tid & 7) * 16) ^ ((rowp & 7) << 4);

#define FSTAGE(buf, t)                                                        \
  {                                                                           \
    int base = (t) * 64;                                                      \
    gload16(Kb + (long)min(base + rowp, 799) * 64 + (swb >> 1),               \
            &lK[buf][wv * 512]);                                              \
    gload16(Kb + (long)min(base + 32 + rowp, 799) * 64 + (swb >> 1),          \
            &lK[buf][2048 + wv * 512]);                                       \
    int vcol = min(base + (swb >> 1), 792);                                   \
    gload16(Vb + (long)rowp * 800 + vcol, &lV[buf][wv * 512]);                \
    gload16(Vb + (long)(32 + rowp) * 800 + vcol, &lV[buf][2048 + wv * 512]);  \
  }

  const int NT = 13;            // ceil(800/64)
  FSTAGE(0, 0);
  FSTAGE(1, 1);
  for (int t = 0; t < NT; ++t) {
    if (t + 1 < NT) { WAITVM(4); } else { WAITVM(0); }
    BARRIER();

    // ---- S^T = K x Q (exp2 domain) ----
    f32x4 st[4];
    __builtin_amdgcn_s_setprio(1);
#pragma unroll
    for (int ns = 0; ns < 4; ++ns) {
      int row = ns * 16 + l15;
      short8 k0 = *(const short8*)((char*)lK[t & 1] + row * 128 + ((lg * 16) ^ ((l15 & 7) << 4)));
      short8 k1 = *(const short8*)((char*)lK[t & 1] + row * 128 + ((64 + lg * 16) ^ ((l15 & 7) << 4)));
      f32x4 z = {};
      z = MFMA16(k0, q0, z);
      z = MFMA16(k1, q1, z);
      st[ns] = z;
    }
    __builtin_amdgcn_s_setprio(0);

    // ---- online softmax (q = l15), defer-max THR=8 ----
    float pv[16];
    float pmax = NEGBIG;
    int tokbase = t * 64 + lg * 4;
#pragma unroll
    for (int ns = 0; ns < 4; ++ns)
#pragma unroll
      for (int r = 0; r < 4; ++r) {
        float v = (tokbase + ns * 16 + r < nk) ? st[ns][r] : NEGBIG;
        pv[ns * 4 + r] = v;
        pmax = fmaxf(pmax, v);
      }
    pmax = fmaxf(pmax, __shfl_xor(pmax, 16));
    pmax = fmaxf(pmax, __shfl_xor(pmax, 32));
    if (__any(pmax > m + 8.0f)) {
      float mn = fmaxf(m, pmax);
      float sc = exp2f(m - mn);
      ls *= sc;
#pragma unroll
      for (int n = 0; n < 4; ++n) oacc[n] *= sc;
      m = mn;
    }
    float lsl = 0.f;
#pragma unroll
    for (int i = 0; i < 16; ++i) { float e = exp2f(pv[i] - m); pv[i] = e; lsl += e; }
    ls += lsl;

    // ---- pack P -> lP (wave-private), b64 swizzled writes ----
#pragma unroll
    for (int ns = 0; ns < 4; ++ns) {
      uint2 val;
      val.x = cvtpk(pv[ns * 4 + 0], pv[ns * 4 + 1]);
      val.y = cvtpk(pv[ns * 4 + 2], pv[ns * 4 + 3]);
      *(uint2*)((char*)(&lP[wv][0]) + l15 * 128 + ((ns * 32 + lg * 8) ^ ((l15 & 7) << 4))) = val;
    }
    asm volatile("" ::: "memory");

    // ---- O^T += V^T x P^T ----
    __builtin_amdgcn_s_setprio(1);
#pragma unroll
    for (int half = 0; half < 2; ++half) {
      short8 pf = *(const short8*)((char*)(&lP[wv][0]) + l15 * 128 +
                                   ((half * 64 + lg * 16) ^ ((l15 & 7) << 4)));
#pragma unroll
      for (int ns2 = 0; ns2 < 4; ++ns2) {
        int row = ns2 * 16 + l15;
        short8 vf = *(const short8*)((char*)lV[t & 1] + row * 128 +
                                     ((half * 64 + lg * 16) ^ ((l15 & 7) << 4)));
        oacc[ns2] = MFMA16(vf, pf, oacc[ns2]);
      }
    }
    __builtin_amdgcn_s_setprio(0);
    BARRIER();
    if (t + 2 < NT) FSTAGE(t & 1, t + 2);
  }
#undef FSTAGE

  // ---- finalize ----
  ls += __shfl_xor(ls, 16);
  ls += __shfl_xor(ls, 32);
  float inv = 1.0f / ls;

  {
    int qrl = wv * 16 + l15;
#pragma unroll
    for (int ns2 = 0; ns2 < 4; ++ns2) {
      uint2 val;
      val.x = (unsigned)f2bf(oacc[ns2][0] * inv) | ((unsigned)f2bf(oacc[ns2][1] * inv) << 16);
      val.y = (unsigned)f2bf(oacc[ns2][2] * inv) | ((unsigned)f2bf(oacc[ns2][3] * inv) << 16);
      *(uint2*)((char*)lK[0] + qrl * 128 + ((ns2 * 32 + lg * 8) ^ ((l15 & 7) << 4))) = val;
    }
  }
  __syncthreads();
#pragma unroll
  for (int p = 0; p < 2; ++p) {
    int o = (p * 256 + tid) * 16;
    int row = o >> 7, colb = o & 127;
    int qg = qt * 64 + row;
    if (qg < nq) {
      float4 v = *(const float4*)((char*)lK[0] + (o & ~127) + (colb ^ ((row & 7) << 4)));
      *(float4*)(Ob + (long)qg * ostr + (colb >> 1)) = v;
    }
  }
}

// ---------- launch ----------
extern "C" void kernel_launch(void* const* d_in, const int* in_sizes, int n_in,
                              void* d_out, int out_size, void* d_ws, size_t ws_size,
                              hipStream_t stream) {
  const float* x      = (const float*)d_in[0];
  const float* gqkv_w = (const float*)d_in[1];
  const float* gqkv_b = (const float*)d_in[2];
  const float* pq_w   = (const float*)d_in[3];
  const float* pq_b   = (const float*)d_in[4];
  const float* pkv_w  = (const float*)d_in[5];
  const float* pkv_b  = (const float*)d_in[6];
  const float* conv_w = (const float*)d_in[7];
  const float* conv_b = (const float*)d_in[8];
  const float* ln_g   = (const float*)d_in[9];
  const float* ln_b   = (const float*)d_in[10];
  const float* proj_w = (const float*)d_in[11];
  const float* proj_b = (const float*)d_in[12];

  char* ws = (char*)d_ws;
  unsigned short* xbf  = (unsigned short*)(ws + 0);           // aliased by cat
  unsigned short* cat  = xbf;
  unsigned short* qg   = (unsigned short*)(ws + 65536000);    // grid Q gathered (*SM2)
  unsigned short* kg   = (unsigned short*)(ws + 98304000);    // grid K gathered
  unsigned short* vg   = (unsigned short*)(ws + 131072000);   // grid V gathered
  unsigned short* qp   = (unsigned short*)(ws + 163840000);   // pool Q (*SM2)
  unsigned short* pr   = (unsigned short*)(ws + 196608000);   // pooled (dead -> vtg)
  float*          cvt  = (float*)        (ws + 209715200);    // conv out (dead -> vtg)
  unsigned short* vtg  = (unsigned short*)(ws + 196608000);   // grid V^T (alias pr+cvt)
  unsigned short* p2   = (unsigned short*)(ws + 235929600);   // ln+gelu (dead -> vtp)
  unsigned short* vtp  = (unsigned short*)(ws + 235929600);   // pool V^T (alias p2)
  unsigned short* kp   = (unsigned short*)(ws + 249036800);   // pool K gathered
  unsigned short* vp   = (unsigned short*)(ws + 255590400);   // pool V gathered
  unsigned short* wtg  = (unsigned short*)(ws + 262144000);   // [768][512]
  unsigned short* wtkv = (unsigned short*)(ws + 263192576);
  unsigned short* wtc  = (unsigned short*)(ws + 263716864);
  unsigned short* wtp  = (unsigned short*)(ws + 264241152);

  // prep
  cast_f32_bf16<<<32000, 256, 0, stream>>>(x, xbf, 64000L * 512);
  wtrans5<<<dim3(1536, 5), 256, 0, stream>>>(gqkv_w, pq_w, pkv_w, conv_w, proj_w, wtg);
  pool_mean<<<12800, 256, 0, stream>>>(xbf, pr);

  // pool branch (small GEMMs keep the 128^2 kernel)
  gemm_bf16<<<dim3(4, 100), 256, 0, stream>>>(pr, wtc, conv_b, cvt, nullptr,
                                              12800, 512, 512, 1);
  ln_gelu<<<12800, 256, 0, stream>>>(cvt, ln_g, ln_b, p2);
  gemm_bf16<<<dim3(4, 100), 256, 0, stream>>>(p2, wtkv, pkv_b, kp, vp,
                                              12800, 512, 512, 3);

  // merged gqkv + pool-Q projection (B = wtg||wtq contiguous, N=1024) — 256^2 kernel
  gemm256<<<dim3(4, 250), 512, 0, stream>>>(xbf, wtg, gqkv_b, pq_b,
                                            qg, kg, vg, qp,
                                            64000, 1024, 512, 2);

  // V transposes (pr/cvt and p2 dead by now)
  vtrans<<<dim3(13, 320), 256, 0, stream>>>(vg, vtg);
  vtrans<<<dim3(13, 64), 256, 0, stream>>>(vp, vtp);

  // attentions -> cat (xbf dead after merged GEMM)
  flash_v4<<<dim3(13, 320), 256, 0, stream>>>(qg, kg, vtg, cat, 0);
  flash_v4<<<dim3(63, 64), 256, 0, stream>>>(qp, kp, vtp, cat, 1);

  // output projection (fp32 out) — 256^2 kernel
  gemm256<<<dim3(2, 250), 512, 0, stream>>>(cat, wtp, proj_b, nullptr,
                                            d_out, nullptr, nullptr, nullptr,
                                            64000, 512, 512, 1);
}

// Round 7
// 615.427 us; speedup vs baseline: 1.0060x; 1.0060x over previous
//
#include <hip/hip_runtime.h>
#include <hip/hip_bf16.h>
#include <math.h>

// ---------- types ----------
typedef short short8 __attribute__((ext_vector_type(8)));
typedef float f32x4 __attribute__((ext_vector_type(4)));

#define MFMA16(a, b, c) __builtin_amdgcn_mfma_f32_16x16x32_bf16((a), (b), (c), 0, 0, 0)
#define NEGBIG (-1e30f)
#define SM2 0.18033688f   // 0.125 * log2(e): QK^T softmax done in exp2 domain

// raw barrier + compiler fence (counted-vmcnt pipeline: loads stay in flight across it)
#define BARRIER() { __builtin_amdgcn_sched_barrier(0); \
                    asm volatile("s_barrier" ::: "memory"); \
                    __builtin_amdgcn_sched_barrier(0); }
#define WAITVM(n) asm volatile("s_waitcnt vmcnt(" #n ")" ::: "memory")

__device__ __forceinline__ unsigned short f2bf(float f) {
  unsigned u = __builtin_bit_cast(unsigned, f);
  u += 0x7FFFu + ((u >> 16) & 1u);   // RNE
  return (unsigned short)(u >> 16);
}
__device__ __forceinline__ float b2f(unsigned short h) {
  return __builtin_bit_cast(float, (unsigned)h << 16);
}
__device__ __forceinline__ unsigned cvtpk(float lo, float hi) {
  unsigned r;
  asm("v_cvt_pk_bf16_f32 %0, %1, %2" : "=v"(r) : "v"(lo), "v"(hi));
  return r;
}
// async global->LDS, 16B/lane; LDS dest = wave-uniform base (+ lane*16 by HW)
__device__ __forceinline__ void gload16(const void* g, void* l) {
  __builtin_amdgcn_global_load_lds((const __attribute__((address_space(1))) unsigned*)g,
                                   (__attribute__((address_space(3))) unsigned*)l, 16, 0, 0);
}

// ---------- small kernels ----------
__global__ __launch_bounds__(256) void cast_f32_bf16(const float* __restrict__ in,
                                                     unsigned short* __restrict__ out,
                                                     long n) {
  long i = ((long)blockIdx.x * 256 + threadIdx.x) * 4;
  if (i + 3 < n) {
    float4 v = *(const float4*)(in + i);
    ushort4 o;
    o.x = f2bf(v.x); o.y = f2bf(v.y); o.z = f2bf(v.z); o.w = f2bf(v.w);
    *(ushort4*)(out + i) = o;
  }
}

// merged transpose of the 5 weight matrices [512,N] fp32 -> [N,512] bf16 (contiguous dst)
__global__ __launch_bounds__(256) void wtrans5(const float* __restrict__ w0,
                                               const float* __restrict__ w1,
                                               const float* __restrict__ w2,
                                               const float* __restrict__ w3,
                                               const float* __restrict__ w4,
                                               unsigned short* __restrict__ dst) {
  int seg = blockIdx.y;
  const float* src; int N; long doff;
  switch (seg) {
    case 0:  src = w0; N = 768; doff = 0;       break;   // gqkv -> wtg
    case 1:  src = w1; N = 256; doff = 393216;  break;   // pq   -> wtq
    case 2:  src = w2; N = 512; doff = 524288;  break;   // pkv  -> wtkv
    case 3:  src = w3; N = 512; doff = 786432;  break;   // conv -> wtc
    default: src = w4; N = 512; doff = 1048576; break;   // proj -> wtp
  }
  int idx = blockIdx.x * 256 + threadIdx.x;
  if (idx < 512 * N) {
    int k = idx / N, n = idx - k * N;
    dst[doff + (long)n * 512 + k] = f2bf(src[idx]);
  }
}

// pooled[b,j,c] = mean_w xbf[b, j*5+w, c]  (bf16 in, bf16 out)
__global__ __launch_bounds__(256) void pool_mean(const unsigned short* __restrict__ x,
                                                 unsigned short* __restrict__ pr) {
  long bi = blockIdx.x;                 // b*800 + j
  const unsigned short* src = x + bi * 2560;
  int c = threadIdx.x * 2;
  float ax = 0.f, ay = 0.f;
#pragma unroll
  for (int w = 0; w < 5; ++w) {
    unsigned v = *(const unsigned*)(src + w * 512 + c);
    ax += b2f((unsigned short)(v & 0xffff));
    ay += b2f((unsigned short)(v >> 16));
  }
  unsigned out = (unsigned)f2bf(ax * 0.2f) | ((unsigned)f2bf(ay * 0.2f) << 16);
  *(unsigned*)(pr + bi * 512 + c) = out;
}

// LayerNorm (eps 1e-5, biased var) + erf-GELU ; fp32 [rows,512] -> bf16
__global__ __launch_bounds__(256) void ln_gelu(const float* __restrict__ in,
                                               const float* __restrict__ g,
                                               const float* __restrict__ be,
                                               unsigned short* __restrict__ out) {
  long row = blockIdx.x;
  const float* src = in + row * 512;
  int tid = threadIdx.x;
  float2 v = *(const float2*)(src + tid * 2);
  float s = v.x + v.y, sq = v.x * v.x + v.y * v.y;
#pragma unroll
  for (int m = 1; m < 64; m <<= 1) {
    s  += __shfl_xor(s, m);
    sq += __shfl_xor(sq, m);
  }
  __shared__ float ss[4], ssq[4];
  int wv = tid >> 6;
  if ((tid & 63) == 0) { ss[wv] = s; ssq[wv] = sq; }
  __syncthreads();
  s  = ss[0] + ss[1] + ss[2] + ss[3];
  sq = ssq[0] + ssq[1] + ssq[2] + ssq[3];
  float mu = s * (1.0f / 512.0f);
  float var = sq * (1.0f / 512.0f) - mu * mu;
  float rs = rsqrtf(var + 1e-5f);
  int c = tid * 2;
#pragma unroll
  for (int e = 0; e < 2; ++e) {
    float xv = (e == 0 ? v.x : v.y);
    float y = (xv - mu) * rs * g[c + e] + be[c + e];
    float ge = 0.5f * y * (1.0f + erff(y * 0.70710678118654752f));
    out[row * 512 + c + e] = f2bf(ge);
  }
}

// ---------- V transpose: src [seq][800][64] -> dst [seq][64][800] ----------
__global__ __launch_bounds__(256) void vtrans(const unsigned short* __restrict__ src,
                                              unsigned short* __restrict__ dst) {
  __shared__ unsigned short tile[64][64];
  int jt = blockIdx.x, s = blockIdx.y;
  int tid = threadIdx.x;
#pragma unroll
  for (int p = 0; p < 2; ++p) {
    int idx = p * 256 + tid;
    int j = idx >> 3, d8 = (idx & 7) * 8;
    int jg = min(jt * 64 + j, 799);
    short8 v = *(const short8*)(src + ((long)s * 800 + jg) * 64 + d8);
    *(short8*)&tile[j][d8] = v;
  }
  __syncthreads();
  int d = tid >> 2, jseg = (tid & 3) * 16;
  if (jt * 64 + jseg < 800) {
    short8 h0, h1;
#pragma unroll
    for (int i = 0; i < 8; ++i) { h0[i] = (short)tile[jseg + i][d]; h1[i] = (short)tile[jseg + 8 + i][d]; }
    unsigned short* o = dst + ((long)s * 64 + d) * 800 + jt * 64 + jseg;
    *(short8*)o = h0;
    *(short8*)(o + 8) = h1;
  }
}

// ---------- small GEMM (pool branch): 128x128 tile, 4 waves, BK=32 ----------
// gmode 1: fp32 out0 [M][N];  gmode 3: kv-split gathered K/V [64][800][64]
__global__ __launch_bounds__(256) void gemm_bf16(const unsigned short* __restrict__ A,
                                                 const unsigned short* __restrict__ Bt,
                                                 const float* __restrict__ bias,
                                                 void* __restrict__ out0, void* __restrict__ out1,
                                                 int M, int N, int K, int gmode) {
  __shared__ unsigned short lA[2][128 * 32];
  __shared__ unsigned short lB[2][128 * 32];
  const int tid = threadIdx.x;
  const int lane = tid & 63, wv = tid >> 6;
  const int wr = wv >> 1, wc = wv & 1;
  const int l15 = lane & 15, lg = lane >> 4;

  const int nwg = gridDim.x * gridDim.y;
  const int bid = blockIdx.y * gridDim.x + blockIdx.x;
  const int w = (bid & 7) * (nwg >> 3) + (bid >> 3);
  const int m0 = (w / gridDim.x) * 128, n0 = (w % gridDim.x) * 128;

  const int r0  = tid >> 2;
  const int sw0 = ((tid & 3) * 16) ^ ((r0 & 3) << 4);
  const unsigned short* As0 = A  + (size_t)(m0 + r0)      * K + (sw0 >> 1);
  const unsigned short* As1 = A  + (size_t)(m0 + 64 + r0) * K + (sw0 >> 1);
  const unsigned short* Bs0 = Bt + (size_t)(n0 + r0)      * K + (sw0 >> 1);
  const unsigned short* Bs1 = Bt + (size_t)(n0 + 64 + r0) * K + (sw0 >> 1);

  f32x4 acc[4][4] = {};

#define GSTAGE(buf, k0)                                   \
  {                                                       \
    gload16(As0 + (k0), &lA[buf][wv * 512]);              \
    gload16(As1 + (k0), &lA[buf][2048 + wv * 512]);       \
    gload16(Bs0 + (k0), &lB[buf][wv * 512]);              \
    gload16(Bs1 + (k0), &lB[buf][2048 + wv * 512]);       \
  }

  const int nt = K >> 5;
  GSTAGE(0, 0);
  if (nt > 1) GSTAGE(1, 32);
  for (int t = 0; t < nt; ++t) {
    if (t + 1 < nt) { WAITVM(4); } else { WAITVM(0); }
    BARRIER();
    short8 af[4], bfr[4];
#pragma unroll
    for (int s2 = 0; s2 < 4; ++s2) {
      int ra = wr * 64 + s2 * 16 + l15;
      int rb = wc * 64 + s2 * 16 + l15;
      af[s2]  = *(const short8*)((char*)lA[t & 1] + ra * 64 + ((lg * 16) ^ ((ra & 3) << 4)));
      bfr[s2] = *(const short8*)((char*)lB[t & 1] + rb * 64 + ((lg * 16) ^ ((rb & 3) << 4)));
    }
#pragma unroll
    for (int i = 0; i < 4; ++i)
#pragma unroll
      for (int j = 0; j < 4; ++j)
        acc[i][j] = MFMA16(af[i], bfr[j], acc[i][j]);
    BARRIER();
    if (t + 2 < nt) GSTAGE(t & 1, (t + 2) * 32);
  }
#undef GSTAGE

#pragma unroll
  for (int i = 0; i < 4; ++i) {
#pragma unroll
    for (int r = 0; r < 4; ++r) {
      int row = m0 + wr * 64 + i * 16 + lg * 4 + r;
      long rg = 0;
      if (gmode == 3) {
        int b = row / 800, jj = row - b * 800;
        rg = (long)b * 204800 + (long)jj * 64;
      }
#pragma unroll
      for (int j = 0; j < 4; ++j) {
        int col = n0 + wc * 64 + j * 16 + l15;
        float vv = acc[i][j][r] + bias[col];
        if (gmode == 1) {
          ((float*)out0)[(size_t)row * N + col] = vv;
        } else {  // gmode 3
          int hh = (col >> 6) & 3, d = col & 63;
          unsigned short* dst = (col < 256) ? (unsigned short*)out0 : (unsigned short*)out1;
          dst[rg + hh * 51200 + d] = f2bf(vv);
        }
      }
    }
  }
}

// ---------- big GEMM: 256x256 tile, 8 waves (2Mx4N), wave-tile 128x64, BK=64 ----------
// 4-phase-per-K-tile schedule (m201 pattern): each phase {ds_read -> barrier ->
// setprio 16 MFMA -> barrier}. Tile staging counted-vmcnt 2-deep (vmcnt(8)).
__global__ __launch_bounds__(512, 2) void gemm256(const unsigned short* __restrict__ A,
                                                  const unsigned short* __restrict__ Bt,
                                                  const float* __restrict__ bias,
                                                  const float* __restrict__ bias2,
                                                  void* __restrict__ out0, void* __restrict__ out1,
                                                  void* __restrict__ out2, void* __restrict__ out3,
                                                  int M, int N, int K, int gmode) {
  __shared__ unsigned short lA[2][256 * 64];   // 32KB per buf
  __shared__ unsigned short lB[2][256 * 64];   // total 128KB
  const int tid = threadIdx.x;
  const int lane = tid & 63, wv = tid >> 6;    // 8 waves
  const int wr = wv >> 2, wc = wv & 3;         // 2M x 4N
  const int l15 = lane & 15, lg = lane >> 4;

  // bijective XCD swizzle (m204)
  const int nwg = gridDim.x * gridDim.y;
  const int bid = blockIdx.y * gridDim.x + blockIdx.x;
  const int q = nwg >> 3, r8 = nwg & 7;
  const int xcd = bid & 7, idx = bid >> 3;
  const int w = (xcd < r8 ? xcd * (q + 1) : r8 * (q + 1) + (xcd - r8) * q) + idx;
  const int m0 = (w / gridDim.x) * 256, n0 = (w % gridDim.x) * 256;

  const int srow = tid >> 3;                                        // 0..63
  const int scol = ((((lane & 7) ^ (lane >> 3)) << 4)) >> 1;        // element offset
  const unsigned short* Ag[4];
  const unsigned short* Bg[4];
#pragma unroll
  for (int g = 0; g < 4; ++g) {
    Ag[g] = A  + (size_t)(m0 + g * 64 + srow) * K + scol;
    Bg[g] = Bt + (size_t)(n0 + g * 64 + srow) * K + scol;
  }

  f32x4 acc[8][4] = {};

#define GSTAGE2(buf, k0)                                            \
  {                                                                 \
    _Pragma("unroll")                                               \
    for (int g = 0; g < 4; ++g)                                     \
      gload16(Ag[g] + (k0), &lA[buf][g * 4096 + wv * 512]);         \
    _Pragma("unroll")                                               \
    for (int g = 0; g < 4; ++g)                                     \
      gload16(Bg[g] + (k0), &lB[buf][g * 4096 + wv * 512]);         \
  }
#define RDA4(ibase, kk)                                             \
  _Pragma("unroll")                                                 \
  for (int i = 0; i < 4; ++i) {                                     \
    int ra = wr * 128 + ((ibase) + i) * 16 + l15;                   \
    af[i] = *(const short8*)(bufA + ra * 128 +                      \
             (((kk) * 64 + lg * 16) ^ ((ra & 7) << 4)));            \
  }
#define RDB4(kk)                                                    \
  _Pragma("unroll")                                                 \
  for (int j = 0; j < 4; ++j) {                                     \
    int rb = wc * 64 + j * 16 + l15;                                \
    bf[j] = *(const short8*)(bufB + rb * 128 +                      \
             (((kk) * 64 + lg * 16) ^ ((rb & 7) << 4)));            \
  }
#define PH_MFMA(ibase)                                              \
  __builtin_amdgcn_s_setprio(1);                                    \
  _Pragma("unroll")                                                 \
  for (int i = 0; i < 4; ++i)                                       \
    _Pragma("unroll")                                               \
    for (int j = 0; j < 4; ++j)                                     \
      acc[(ibase) + i][j] = MFMA16(af[i], bf[j], acc[(ibase) + i][j]); \
  __builtin_amdgcn_s_setprio(0);

  const int nt = K >> 6;                       // BK=64
  GSTAGE2(0, 0);
  if (nt > 1) GSTAGE2(1, 64);
  for (int t = 0; t < nt; ++t) {
    if (t + 1 < nt) { WAITVM(8); } else { WAITVM(0); }
    BARRIER();
    const char* bufA = (const char*)lA[t & 1];
    const char* bufB = (const char*)lB[t & 1];
    short8 af[4], bf[4];
    // phase 0: kk=0, rows 0..3
    RDA4(0, 0); RDB4(0);
    BARRIER();
    PH_MFMA(0);
    BARRIER();
    // phase 1: kk=0, rows 4..7
    RDA4(4, 0);
    BARRIER();
    PH_MFMA(4);
    BARRIER();
    // phase 2: kk=1, rows 0..3
    RDA4(0, 1); RDB4(1);
    BARRIER();
    PH_MFMA(0);
    BARRIER();
    // phase 3: kk=1, rows 4..7
    RDA4(4, 1);
    BARRIER();
    PH_MFMA(4);
    BARRIER();
    if (t + 2 < nt) GSTAGE2(t & 1, (t + 2) * 64);
  }
#undef GSTAGE2
#undef RDA4
#undef RDB4
#undef PH_MFMA

  // ---- epilogue ----
#pragma unroll
  for (int i = 0; i < 8; ++i) {
#pragma unroll
    for (int rr = 0; rr < 4; ++rr) {
      int row = m0 + wr * 128 + i * 16 + lg * 4 + rr;
      long rg = 0, rq = 0;
      if (gmode == 2) {
        int b = row / 4000, l = row - b * 4000;
        int jj = l / 5, ww = l - jj * 5;
        rg = (long)(b * 5 + ww) * 204800 + (long)jj * 64;
        rq = (long)row * 256;
      }
#pragma unroll
      for (int j = 0; j < 4; ++j) {
        int col = n0 + wc * 64 + j * 16 + l15;
        float vv = acc[i][j][rr];
        if (gmode == 1) {
          ((float*)out0)[(size_t)row * N + col] = vv + bias[col];
        } else {  // gmode 2
          vv += (col < 768) ? bias[col] : bias2[col - 768];
          int sec = col >> 8;
          if (sec == 3) {
            ((unsigned short*)out3)[rq + (col - 768)] = f2bf(vv * SM2);
          } else {
            int hh = (col >> 6) & 3, d = col & 63;
            unsigned short* dst = (sec == 0) ? (unsigned short*)out0
                                 : (sec == 1) ? (unsigned short*)out1 : (unsigned short*)out2;
            dst[rg + hh * 51200 + d] = f2bf(sec == 0 ? vv * SM2 : vv);
          }
        }
      }
    }
  }
}

// ---------- flash attention v5: merged grid+pool, counted-vmcnt dbuf pipeline ----------
// 8192 blocks: w<4160 -> grid attn (sidx=w/13, qt=w%13); else pool (sidx=(w-4160)/63).
__global__ __launch_bounds__(256) void flash_v5(const unsigned short* __restrict__ qg,
                                                const unsigned short* __restrict__ kg,
                                                const unsigned short* __restrict__ vtg,
                                                const unsigned short* __restrict__ qp,
                                                const unsigned short* __restrict__ kp,
                                                const unsigned short* __restrict__ vtp,
                                                unsigned short* __restrict__ cat) {
  __shared__ unsigned short lK[2][64 * 64];   // [tok][d] swizzled (byte ^= (tok&7)<<4)
  __shared__ unsigned short lV[2][64 * 64];   // [d][tok] swizzled
  __shared__ unsigned short lP[4][16 * 64];   // per-wave [q16][tok64] swizzled

  const int tid = threadIdx.x, lane = tid & 63, wv = tid >> 6;
  const int l15 = lane & 15, lg = lane >> 4;

  const int bid = blockIdx.x;
  const int w = (bid & 7) * 1024 + (bid >> 3);   // XCD-contiguous chunks
  int qt, sidx;
  const unsigned short *Kb, *Vb, *Qb;
  unsigned short* Ob;
  long qstr, ostr;
  int nq;
  const int nk = 800;
  if (w < 4160) {                     // grid attention
    sidx = w / 13; qt = w - sidx * 13;
    Kb = kg + (long)sidx * 51200;
    Vb = vtg + (long)sidx * 51200;
    Qb = qg + (long)sidx * 51200; qstr = 64;
    int b = sidx / 20, rem = sidx % 20, ww = rem >> 2, h = rem & 3;
    Ob = cat + ((long)b * 4000 + ww) * 512 + h * 64; ostr = 2560;
    nq = 800;
  } else {                            // pool attention
    int w2 = w - 4160;
    sidx = w2 / 63; qt = w2 - sidx * 63;
    Kb = kp + (long)sidx * 51200;
    Vb = vtp + (long)sidx * 51200;
    int b = sidx >> 2, h = sidx & 3;
    Qb = qp + (long)b * 4000 * 256 + h * 64; qstr = 256;
    Ob = cat + (long)b * 4000 * 512 + 256 + h * 64; ostr = 512;
    nq = 4000;
  }

  int qrow = qt * 64 + wv * 16 + l15;
  int qrc = min(qrow, nq - 1);
  short8 q0 = *(const short8*)(Qb + (long)qrc * qstr + lg * 8);
  short8 q1 = *(const short8*)(Qb + (long)qrc * qstr + 32 + lg * 8);

  float m = NEGBIG, ls = 0.f;
  f32x4 oacc[4] = {};

  const int rowp = tid >> 3;
  const int swb  = ((tid & 7) * 16) ^ ((rowp & 7) << 4);

#define FSTAGE(buf, t)                                                        \
  {                                                                           \
    int base = (t) * 64;                                                      \
    gload16(Kb + (long)min(base + rowp, 799) * 64 + (swb >> 1),               \
            &lK[buf][wv * 512]);                                              \
    gload16(Kb + (long)min(base + 32 + rowp, 799) * 64 + (swb >> 1),          \
            &lK[buf][2048 + wv * 512]);                                       \
    int vcol = min(base + (swb >> 1), 792);                                   \
    gload16(Vb + (long)rowp * 800 + vcol, &lV[buf][wv * 512]);                \
    gload16(Vb + (long)(32 + rowp) * 800 + vcol, &lV[buf][2048 + wv * 512]);  \
  }

  const int NT = 13;            // ceil(800/64)
  FSTAGE(0, 0);
  FSTAGE(1, 1);
  for (int t = 0; t < NT; ++t) {
    if (t + 1 < NT) { WAITVM(4); } else { WAITVM(0); }
    BARRIER();

    // ---- S^T = K x Q (exp2 domain) ----
    f32x4 st[4];
    __builtin_amdgcn_s_setprio(1);
#pragma unroll
    for (int ns = 0; ns < 4; ++ns) {
      int row = ns * 16 + l15;
      short8 k0 = *(const short8*)((char*)lK[t & 1] + row * 128 + ((lg * 16) ^ ((l15 & 7) << 4)));
      short8 k1 = *(const short8*)((char*)lK[t & 1] + row * 128 + ((64 + lg * 16) ^ ((l15 & 7) << 4)));
      f32x4 z = {};
      z = MFMA16(k0, q0, z);
      z = MFMA16(k1, q1, z);
      st[ns] = z;
    }
    __builtin_amdgcn_s_setprio(0);

    // ---- online softmax (q = l15), defer-max THR=8 ----
    float pv[16];
    float pmax = NEGBIG;
    int tokbase = t * 64 + lg * 4;
#pragma unroll
    for (int ns = 0; ns < 4; ++ns)
#pragma unroll
      for (int r = 0; r < 4; ++r) {
        float v = (tokbase + ns * 16 + r < nk) ? st[ns][r] : NEGBIG;
        pv[ns * 4 + r] = v;
        pmax = fmaxf(pmax, v);
      }
    pmax = fmaxf(pmax, __shfl_xor(pmax, 16));
    pmax = fmaxf(pmax, __shfl_xor(pmax, 32));
    if (__any(pmax > m + 8.0f)) {
      float mn = fmaxf(m, pmax);
      float sc = exp2f(m - mn);
      ls *= sc;
#pragma unroll
      for (int n = 0; n < 4; ++n) oacc[n] *= sc;
      m = mn;
    }
    float lsl = 0.f;
#pragma unroll
    for (int i = 0; i < 16; ++i) { float e = exp2f(pv[i] - m); pv[i] = e; lsl += e; }
    ls += lsl;

    // ---- pack P -> lP (wave-private), b64 swizzled writes ----
#pragma unroll
    for (int ns = 0; ns < 4; ++ns) {
      uint2 val;
      val.x = cvtpk(pv[ns * 4 + 0], pv[ns * 4 + 1]);
      val.y = cvtpk(pv[ns * 4 + 2], pv[ns * 4 + 3]);
      *(uint2*)((char*)(&lP[wv][0]) + l15 * 128 + ((ns * 32 + lg * 8) ^ ((l15 & 7) << 4))) = val;
    }
    asm volatile("" ::: "memory");

    // ---- O^T += V^T x P^T ----
    __builtin_amdgcn_s_setprio(1);
#pragma unroll
    for (int half = 0; half < 2; ++half) {
      short8 pf = *(const short8*)((char*)(&lP[wv][0]) + l15 * 128 +
                                   ((half * 64 + lg * 16) ^ ((l15 & 7) << 4)));
#pragma unroll
      for (int ns2 = 0; ns2 < 4; ++ns2) {
        int row = ns2 * 16 + l15;
        short8 vf = *(const short8*)((char*)lV[t & 1] + row * 128 +
                                     ((half * 64 + lg * 16) ^ ((l15 & 7) << 4)));
        oacc[ns2] = MFMA16(vf, pf, oacc[ns2]);
      }
    }
    __builtin_amdgcn_s_setprio(0);
    BARRIER();
    if (t + 2 < NT) FSTAGE(t & 1, t + 2);
  }
#undef FSTAGE

  // ---- finalize ----
  ls += __shfl_xor(ls, 16);
  ls += __shfl_xor(ls, 32);
  float inv = 1.0f / ls;

  {
    int qrl = wv * 16 + l15;
#pragma unroll
    for (int ns2 = 0; ns2 < 4; ++ns2) {
      uint2 val;
      val.x = (unsigned)f2bf(oacc[ns2][0] * inv) | ((unsigned)f2bf(oacc[ns2][1] * inv) << 16);
      val.y = (unsigned)f2bf(oacc[ns2][2] * inv) | ((unsigned)f2bf(oacc[ns2][3] * inv) << 16);
      *(uint2*)((char*)lK[0] + qrl * 128 + ((ns2 * 32 + lg * 8) ^ ((l15 & 7) << 4))) = val;
    }
  }
  __syncthreads();
#pragma unroll
  for (int p = 0; p < 2; ++p) {
    int o = (p * 256 + tid) * 16;
    int row = o >> 7, colb = o & 127;
    int qg2 = qt * 64 + row;
    if (qg2 < nq) {
      float4 v = *(const float4*)((char*)lK[0] + (o & ~127) + (colb ^ ((row & 7) << 4)));
      *(float4*)(Ob + (long)qg2 * ostr + (colb >> 1)) = v;
    }
  }
}

// ---------- launch ----------
extern "C" void kernel_launch(void* const* d_in, const int* in_sizes, int n_in,
                              void* d_out, int out_size, void* d_ws, size_t ws_size,
                              hipStream_t stream) {
  const float* x      = (const float*)d_in[0];
  const float* gqkv_w = (const float*)d_in[1];
  const float* gqkv_b = (const float*)d_in[2];
  const float* pq_w   = (const float*)d_in[3];
  const float* pq_b   = (const float*)d_in[4];
  const float* pkv_w  = (const float*)d_in[5];
  const float* pkv_b  = (const float*)d_in[6];
  const float* conv_w = (const float*)d_in[7];
  const float* conv_b = (const float*)d_in[8];
  const float* ln_g   = (const float*)d_in[9];
  const float* ln_b   = (const float*)d_in[10];
  const float* proj_w = (const float*)d_in[11];
  const float* proj_b = (const float*)d_in[12];

  char* ws = (char*)d_ws;
  unsigned short* xbf  = (unsigned short*)(ws + 0);           // aliased by cat
  unsigned short* cat  = xbf;
  unsigned short* qg   = (unsigned short*)(ws + 65536000);    // grid Q gathered (*SM2)
  unsigned short* kg   = (unsigned short*)(ws + 98304000);    // grid K gathered
  unsigned short* vg   = (unsigned short*)(ws + 131072000);   // grid V gathered
  unsigned short* qp   = (unsigned short*)(ws + 163840000);   // pool Q (*SM2)
  unsigned short* pr   = (unsigned short*)(ws + 196608000);   // pooled (dead -> vtg)
  float*          cvt  = (float*)        (ws + 209715200);    // conv out (dead -> vtg)
  unsigned short* vtg  = (unsigned short*)(ws + 196608000);   // grid V^T (alias pr+cvt)
  unsigned short* p2   = (unsigned short*)(ws + 235929600);   // ln+gelu (dead -> vtp)
  unsigned short* vtp  = (unsigned short*)(ws + 235929600);   // pool V^T (alias p2)
  unsigned short* kp   = (unsigned short*)(ws + 249036800);   // pool K gathered
  unsigned short* vp   = (unsigned short*)(ws + 255590400);   // pool V gathered
  unsigned short* wtg  = (unsigned short*)(ws + 262144000);   // [768][512]
  unsigned short* wtkv = (unsigned short*)(ws + 263192576);
  unsigned short* wtc  = (unsigned short*)(ws + 263716864);
  unsigned short* wtp  = (unsigned short*)(ws + 264241152);

  // prep
  cast_f32_bf16<<<32000, 256, 0, stream>>>(x, xbf, 64000L * 512);
  wtrans5<<<dim3(1536, 5), 256, 0, stream>>>(gqkv_w, pq_w, pkv_w, conv_w, proj_w, wtg);
  pool_mean<<<12800, 256, 0, stream>>>(xbf, pr);

  // pool branch (small GEMMs keep the 128^2 kernel)
  gemm_bf16<<<dim3(4, 100), 256, 0, stream>>>(pr, wtc, conv_b, cvt, nullptr,
                                              12800, 512, 512, 1);
  ln_gelu<<<12800, 256, 0, stream>>>(cvt, ln_g, ln_b, p2);
  gemm_bf16<<<dim3(4, 100), 256, 0, stream>>>(p2, wtkv, pkv_b, kp, vp,
                                              12800, 512, 512, 3);

  // merged gqkv + pool-Q projection (B = wtg||wtq contiguous, N=1024) — 256^2 4-phase
  gemm256<<<dim3(4, 250), 512, 0, stream>>>(xbf, wtg, gqkv_b, pq_b,
                                            qg, kg, vg, qp,
                                            64000, 1024, 512, 2);

  // V transposes (pr/cvt and p2 dead by now)
  vtrans<<<dim3(13, 320), 256, 0, stream>>>(vg, vtg);
  vtrans<<<dim3(13, 64), 256, 0, stream>>>(vp, vtp);

  // merged attentions -> cat (xbf dead after merged GEMM)
  flash_v5<<<8192, 256, 0, stream>>>(qg, kg, vtg, qp, kp, vtp, cat);

  // output projection (fp32 out) — 256^2 4-phase
  gemm256<<<dim3(2, 250), 512, 0, stream>>>(cat, wtp, proj_b, nullptr,
                                            d_out, nullptr, nullptr, nullptr,
                                            64000, 512, 512, 1);
}

// Round 8
// 598.589 us; speedup vs baseline: 1.0343x; 1.0281x over previous
//
#include <hip/hip_runtime.h>
#include <hip/hip_bf16.h>
#include <math.h>

// ---------- types ----------
typedef short short8 __attribute__((ext_vector_type(8)));
typedef float f32x4 __attribute__((ext_vector_type(4)));

#define MFMA16(a, b, c) __builtin_amdgcn_mfma_f32_16x16x32_bf16((a), (b), (c), 0, 0, 0)
#define NEGBIG (-1e30f)
#define SM2 0.18033688f   // 0.125 * log2(e): QK^T softmax done in exp2 domain

// raw barrier + compiler fence (counted-vmcnt pipeline: loads stay in flight across it)
#define BARRIER() { __builtin_amdgcn_sched_barrier(0); \
                    asm volatile("s_barrier" ::: "memory"); \
                    __builtin_amdgcn_sched_barrier(0); }
#define WAITVM(n) asm volatile("s_waitcnt vmcnt(" #n ")" ::: "memory")

__device__ __forceinline__ unsigned short f2bf(float f) {
  unsigned u = __builtin_bit_cast(unsigned, f);
  u += 0x7FFFu + ((u >> 16) & 1u);   // RNE
  return (unsigned short)(u >> 16);
}
__device__ __forceinline__ float b2f(unsigned short h) {
  return __builtin_bit_cast(float, (unsigned)h << 16);
}
__device__ __forceinline__ unsigned cvtpk(float lo, float hi) {
  unsigned r;
  asm("v_cvt_pk_bf16_f32 %0, %1, %2" : "=v"(r) : "v"(lo), "v"(hi));
  return r;
}
// async global->LDS, 16B/lane; LDS dest = wave-uniform base (+ lane*16 by HW)
__device__ __forceinline__ void gload16(const void* g, void* l) {
  __builtin_amdgcn_global_load_lds((const __attribute__((address_space(1))) unsigned*)g,
                                   (__attribute__((address_space(3))) unsigned*)l, 16, 0, 0);
}

// ---------- small kernels ----------
__global__ __launch_bounds__(256) void cast_f32_bf16(const float* __restrict__ in,
                                                     unsigned short* __restrict__ out,
                                                     long n) {
  long i = ((long)blockIdx.x * 256 + threadIdx.x) * 4;
  if (i + 3 < n) {
    float4 v = *(const float4*)(in + i);
    ushort4 o;
    o.x = f2bf(v.x); o.y = f2bf(v.y); o.z = f2bf(v.z); o.w = f2bf(v.w);
    *(ushort4*)(out + i) = o;
  }
}

// merged transpose of the 5 weight matrices [512,N] fp32 -> [N,512] bf16 (contiguous dst)
__global__ __launch_bounds__(256) void wtrans5(const float* __restrict__ w0,
                                               const float* __restrict__ w1,
                                               const float* __restrict__ w2,
                                               const float* __restrict__ w3,
                                               const float* __restrict__ w4,
                                               unsigned short* __restrict__ dst) {
  int seg = blockIdx.y;
  const float* src; int N; long doff;
  switch (seg) {
    case 0:  src = w0; N = 768; doff = 0;       break;   // gqkv -> wtg
    case 1:  src = w1; N = 256; doff = 393216;  break;   // pq   -> wtq
    case 2:  src = w2; N = 512; doff = 524288;  break;   // pkv  -> wtkv
    case 3:  src = w3; N = 512; doff = 786432;  break;   // conv -> wtc
    default: src = w4; N = 512; doff = 1048576; break;   // proj -> wtp
  }
  int idx = blockIdx.x * 256 + threadIdx.x;
  if (idx < 512 * N) {
    int k = idx / N, n = idx - k * N;
    dst[doff + (long)n * 512 + k] = f2bf(src[idx]);
  }
}

// pooled[b,j,c] = mean_w xbf[b, j*5+w, c]  (bf16 in, bf16 out)
__global__ __launch_bounds__(256) void pool_mean(const unsigned short* __restrict__ x,
                                                 unsigned short* __restrict__ pr) {
  long bi = blockIdx.x;                 // b*800 + j
  const unsigned short* src = x + bi * 2560;
  int c = threadIdx.x * 2;
  float ax = 0.f, ay = 0.f;
#pragma unroll
  for (int w = 0; w < 5; ++w) {
    unsigned v = *(const unsigned*)(src + w * 512 + c);
    ax += b2f((unsigned short)(v & 0xffff));
    ay += b2f((unsigned short)(v >> 16));
  }
  unsigned out = (unsigned)f2bf(ax * 0.2f) | ((unsigned)f2bf(ay * 0.2f) << 16);
  *(unsigned*)(pr + bi * 512 + c) = out;
}

// LayerNorm (eps 1e-5, biased var) + erf-GELU ; fp32 [rows,512] -> bf16
__global__ __launch_bounds__(256) void ln_gelu(const float* __restrict__ in,
                                               const float* __restrict__ g,
                                               const float* __restrict__ be,
                                               unsigned short* __restrict__ out) {
  long row = blockIdx.x;
  const float* src = in + row * 512;
  int tid = threadIdx.x;
  float2 v = *(const float2*)(src + tid * 2);
  float s = v.x + v.y, sq = v.x * v.x + v.y * v.y;
#pragma unroll
  for (int m = 1; m < 64; m <<= 1) {
    s  += __shfl_xor(s, m);
    sq += __shfl_xor(sq, m);
  }
  __shared__ float ss[4], ssq[4];
  int wv = tid >> 6;
  if ((tid & 63) == 0) { ss[wv] = s; ssq[wv] = sq; }
  __syncthreads();
  s  = ss[0] + ss[1] + ss[2] + ss[3];
  sq = ssq[0] + ssq[1] + ssq[2] + ssq[3];
  float mu = s * (1.0f / 512.0f);
  float var = sq * (1.0f / 512.0f) - mu * mu;
  float rs = rsqrtf(var + 1e-5f);
  int c = tid * 2;
#pragma unroll
  for (int e = 0; e < 2; ++e) {
    float xv = (e == 0 ? v.x : v.y);
    float y = (xv - mu) * rs * g[c + e] + be[c + e];
    float ge = 0.5f * y * (1.0f + erff(y * 0.70710678118654752f));
    out[row * 512 + c + e] = f2bf(ge);
  }
}

// ---------- V transpose: src [seq][800][64] -> dst [seq][64][800] ----------
__global__ __launch_bounds__(256) void vtrans(const unsigned short* __restrict__ src,
                                              unsigned short* __restrict__ dst) {
  __shared__ unsigned short tile[64][64];
  int jt = blockIdx.x, s = blockIdx.y;
  int tid = threadIdx.x;
#pragma unroll
  for (int p = 0; p < 2; ++p) {
    int idx = p * 256 + tid;
    int j = idx >> 3, d8 = (idx & 7) * 8;
    int jg = min(jt * 64 + j, 799);
    short8 v = *(const short8*)(src + ((long)s * 800 + jg) * 64 + d8);
    *(short8*)&tile[j][d8] = v;
  }
  __syncthreads();
  int d = tid >> 2, jseg = (tid & 3) * 16;
  if (jt * 64 + jseg < 800) {
    short8 h0, h1;
#pragma unroll
    for (int i = 0; i < 8; ++i) { h0[i] = (short)tile[jseg + i][d]; h1[i] = (short)tile[jseg + 8 + i][d]; }
    unsigned short* o = dst + ((long)s * 64 + d) * 800 + jt * 64 + jseg;
    *(short8*)o = h0;
    *(short8*)(o + 8) = h1;
  }
}

// ---------- small GEMM (pool branch): 128x128 tile, 4 waves, BK=32 ----------
// gmode 1: fp32 out0 [M][N];  gmode 3: kv-split gathered K/V [64][800][64]
__global__ __launch_bounds__(256) void gemm_bf16(const unsigned short* __restrict__ A,
                                                 const unsigned short* __restrict__ Bt,
                                                 const float* __restrict__ bias,
                                                 void* __restrict__ out0, void* __restrict__ out1,
                                                 int M, int N, int K, int gmode) {
  __shared__ unsigned short lA[2][128 * 32];
  __shared__ unsigned short lB[2][128 * 32];
  const int tid = threadIdx.x;
  const int lane = tid & 63, wv = tid >> 6;
  const int wr = wv >> 1, wc = wv & 1;
  const int l15 = lane & 15, lg = lane >> 4;

  const int nwg = gridDim.x * gridDim.y;
  const int bid = blockIdx.y * gridDim.x + blockIdx.x;
  const int w = (bid & 7) * (nwg >> 3) + (bid >> 3);
  const int m0 = (w / gridDim.x) * 128, n0 = (w % gridDim.x) * 128;

  const int r0  = tid >> 2;
  const int sw0 = ((tid & 3) * 16) ^ ((r0 & 3) << 4);
  const unsigned short* As0 = A  + (size_t)(m0 + r0)      * K + (sw0 >> 1);
  const unsigned short* As1 = A  + (size_t)(m0 + 64 + r0) * K + (sw0 >> 1);
  const unsigned short* Bs0 = Bt + (size_t)(n0 + r0)      * K + (sw0 >> 1);
  const unsigned short* Bs1 = Bt + (size_t)(n0 + 64 + r0) * K + (sw0 >> 1);

  f32x4 acc[4][4] = {};

#define GSTAGE(buf, k0)                                   \
  {                                                       \
    gload16(As0 + (k0), &lA[buf][wv * 512]);              \
    gload16(As1 + (k0), &lA[buf][2048 + wv * 512]);       \
    gload16(Bs0 + (k0), &lB[buf][wv * 512]);              \
    gload16(Bs1 + (k0), &lB[buf][2048 + wv * 512]);       \
  }

  const int nt = K >> 5;
  GSTAGE(0, 0);
  if (nt > 1) GSTAGE(1, 32);
  for (int t = 0; t < nt; ++t) {
    if (t + 1 < nt) { WAITVM(4); } else { WAITVM(0); }
    BARRIER();
    short8 af[4], bfr[4];
#pragma unroll
    for (int s2 = 0; s2 < 4; ++s2) {
      int ra = wr * 64 + s2 * 16 + l15;
      int rb = wc * 64 + s2 * 16 + l15;
      af[s2]  = *(const short8*)((char*)lA[t & 1] + ra * 64 + ((lg * 16) ^ ((ra & 3) << 4)));
      bfr[s2] = *(const short8*)((char*)lB[t & 1] + rb * 64 + ((lg * 16) ^ ((rb & 3) << 4)));
    }
#pragma unroll
    for (int i = 0; i < 4; ++i)
#pragma unroll
      for (int j = 0; j < 4; ++j)
        acc[i][j] = MFMA16(af[i], bfr[j], acc[i][j]);
    BARRIER();
    if (t + 2 < nt) GSTAGE(t & 1, (t + 2) * 32);
  }
#undef GSTAGE

#pragma unroll
  for (int i = 0; i < 4; ++i) {
#pragma unroll
    for (int r = 0; r < 4; ++r) {
      int row = m0 + wr * 64 + i * 16 + lg * 4 + r;
      long rg = 0;
      if (gmode == 3) {
        int b = row / 800, jj = row - b * 800;
        rg = (long)b * 204800 + (long)jj * 64;
      }
#pragma unroll
      for (int j = 0; j < 4; ++j) {
        int col = n0 + wc * 64 + j * 16 + l15;
        float vv = acc[i][j][r] + bias[col];
        if (gmode == 1) {
          ((float*)out0)[(size_t)row * N + col] = vv;
        } else {  // gmode 3
          int hh = (col >> 6) & 3, d = col & 63;
          unsigned short* dst = (col < 256) ? (unsigned short*)out0 : (unsigned short*)out1;
          dst[rg + hh * 51200 + d] = f2bf(vv);
        }
      }
    }
  }
}

// ---------- big GEMM: 256x256 tile, 8 waves (2Mx4N), wave-tile 128x64, BK=64 ----------
// 4-phase-per-K-tile schedule; tile staging counted-vmcnt 2-deep (vmcnt(8)).
__global__ __launch_bounds__(512, 2) void gemm256(const unsigned short* __restrict__ A,
                                                  const unsigned short* __restrict__ Bt,
                                                  const float* __restrict__ bias,
                                                  const float* __restrict__ bias2,
                                                  void* __restrict__ out0, void* __restrict__ out1,
                                                  void* __restrict__ out2, void* __restrict__ out3,
                                                  int M, int N, int K, int gmode) {
  __shared__ unsigned short lA[2][256 * 64];   // 32KB per buf
  __shared__ unsigned short lB[2][256 * 64];   // total 128KB
  const int tid = threadIdx.x;
  const int lane = tid & 63, wv = tid >> 6;    // 8 waves
  const int wr = wv >> 2, wc = wv & 3;         // 2M x 4N
  const int l15 = lane & 15, lg = lane >> 4;

  // bijective XCD swizzle (m204)
  const int nwg = gridDim.x * gridDim.y;
  const int bid = blockIdx.y * gridDim.x + blockIdx.x;
  const int q = nwg >> 3, r8 = nwg & 7;
  const int xcd = bid & 7, idx = bid >> 3;
  const int w = (xcd < r8 ? xcd * (q + 1) : r8 * (q + 1) + (xcd - r8) * q) + idx;
  const int m0 = (w / gridDim.x) * 256, n0 = (w % gridDim.x) * 256;

  const int srow = tid >> 3;                                        // 0..63
  const int scol = ((((lane & 7) ^ (lane >> 3)) << 4)) >> 1;        // element offset
  const unsigned short* Ag[4];
  const unsigned short* Bg[4];
#pragma unroll
  for (int g = 0; g < 4; ++g) {
    Ag[g] = A  + (size_t)(m0 + g * 64 + srow) * K + scol;
    Bg[g] = Bt + (size_t)(n0 + g * 64 + srow) * K + scol;
  }

  f32x4 acc[8][4] = {};

#define GSTAGE2(buf, k0)                                            \
  {                                                                 \
    _Pragma("unroll")                                               \
    for (int g = 0; g < 4; ++g)                                     \
      gload16(Ag[g] + (k0), &lA[buf][g * 4096 + wv * 512]);         \
    _Pragma("unroll")                                               \
    for (int g = 0; g < 4; ++g)                                     \
      gload16(Bg[g] + (k0), &lB[buf][g * 4096 + wv * 512]);         \
  }
#define RDA4(ibase, kk)                                             \
  _Pragma("unroll")                                                 \
  for (int i = 0; i < 4; ++i) {                                     \
    int ra = wr * 128 + ((ibase) + i) * 16 + l15;                   \
    af[i] = *(const short8*)(bufA + ra * 128 +                      \
             (((kk) * 64 + lg * 16) ^ ((ra & 7) << 4)));            \
  }
#define RDB4(kk)                                                    \
  _Pragma("unroll")                                                 \
  for (int j = 0; j < 4; ++j) {                                     \
    int rb = wc * 64 + j * 16 + l15;                                \
    bf[j] = *(const short8*)(bufB + rb * 128 +                      \
             (((kk) * 64 + lg * 16) ^ ((rb & 7) << 4)));            \
  }
#define PH_MFMA(ibase)                                              \
  __builtin_amdgcn_s_setprio(1);                                    \
  _Pragma("unroll")                                                 \
  for (int i = 0; i < 4; ++i)                                       \
    _Pragma("unroll")                                               \
    for (int j = 0; j < 4; ++j)                                     \
      acc[(ibase) + i][j] = MFMA16(af[i], bf[j], acc[(ibase) + i][j]); \
  __builtin_amdgcn_s_setprio(0);

  const int nt = K >> 6;                       // BK=64
  GSTAGE2(0, 0);
  if (nt > 1) GSTAGE2(1, 64);
  for (int t = 0; t < nt; ++t) {
    if (t + 1 < nt) { WAITVM(8); } else { WAITVM(0); }
    BARRIER();
    const char* bufA = (const char*)lA[t & 1];
    const char* bufB = (const char*)lB[t & 1];
    short8 af[4], bf[4];
    RDA4(0, 0); RDB4(0);
    BARRIER();
    PH_MFMA(0);
    BARRIER();
    RDA4(4, 0);
    BARRIER();
    PH_MFMA(4);
    BARRIER();
    RDA4(0, 1); RDB4(1);
    BARRIER();
    PH_MFMA(0);
    BARRIER();
    RDA4(4, 1);
    BARRIER();
    PH_MFMA(4);
    BARRIER();
    if (t + 2 < nt) GSTAGE2(t & 1, (t + 2) * 64);
  }
#undef GSTAGE2
#undef RDA4
#undef RDB4
#undef PH_MFMA

  // ---- epilogue ----
#pragma unroll
  for (int i = 0; i < 8; ++i) {
#pragma unroll
    for (int rr = 0; rr < 4; ++rr) {
      int row = m0 + wr * 128 + i * 16 + lg * 4 + rr;
      long rg = 0, rq = 0;
      if (gmode == 2) {
        int b = row / 4000, l = row - b * 4000;
        int jj = l / 5, ww = l - jj * 5;
        rg = (long)(b * 5 + ww) * 204800 + (long)jj * 64;
        rq = (long)row * 256;
      }
#pragma unroll
      for (int j = 0; j < 4; ++j) {
        int col = n0 + wc * 64 + j * 16 + l15;
        float vv = acc[i][j][rr];
        if (gmode == 1) {
          ((float*)out0)[(size_t)row * N + col] = vv + bias[col];
        } else {  // gmode 2
          vv += (col < 768) ? bias[col] : bias2[col - 768];
          int sec = col >> 8;
          if (sec == 3) {
            ((unsigned short*)out3)[rq + (col - 768)] = f2bf(vv * SM2);
          } else {
            int hh = (col >> 6) & 3, d = col & 63;
            unsigned short* dst = (sec == 0) ? (unsigned short*)out0
                                 : (sec == 1) ? (unsigned short*)out1 : (unsigned short*)out2;
            dst[rg + hh * 51200 + d] = f2bf(sec == 0 ? vv * SM2 : vv);
          }
        }
      }
    }
  }
}

// ---------- flash attention v6: 8 waves, QBLK=128, mask-hoisted, counted-vmcnt ----------
// grid: 2240 grid-attn blocks (sidx*7+qt) then 2048 pool blocks (sidx*32+qt). 4288 total.
__global__ __launch_bounds__(512) void flash_v6(const unsigned short* __restrict__ qg,
                                                const unsigned short* __restrict__ kg,
                                                const unsigned short* __restrict__ vtg,
                                                const unsigned short* __restrict__ qp,
                                                const unsigned short* __restrict__ kp,
                                                const unsigned short* __restrict__ vtp,
                                                unsigned short* __restrict__ cat) {
  __shared__ unsigned short lK[2][64 * 64];   // [tok][d] swizzled (byte ^= (tok&7)<<4), 16KB
  __shared__ unsigned short lV[2][64 * 64];   // [d][tok] swizzled, 16KB
  __shared__ unsigned short lP[8][16 * 64];   // per-wave [q16][tok64] swizzled, 16KB

  const int tid = threadIdx.x, lane = tid & 63, wv = tid >> 6;   // 8 waves
  const int l15 = lane & 15, lg = lane >> 4;

  const int bid = blockIdx.x;
  const int w = (bid & 7) * 536 + (bid >> 3);    // XCD-contiguous chunks (4288 = 8*536)
  int qt, sidx;
  const unsigned short *Kb, *Vb, *Qb;
  unsigned short* Ob;
  long qstr, ostr;
  int nq;
  if (w < 2240) {                     // grid attention: 320 seq-heads x 7 q-tiles
    sidx = w / 7; qt = w - sidx * 7;
    Kb = kg + (long)sidx * 51200;
    Vb = vtg + (long)sidx * 51200;
    Qb = qg + (long)sidx * 51200; qstr = 64;
    int b = sidx / 20, rem = sidx % 20, ww = rem >> 2, h = rem & 3;
    Ob = cat + ((long)b * 4000 + ww) * 512 + h * 64; ostr = 2560;
    nq = 800;
  } else {                            // pool attention: 64 seq-heads x 32 q-tiles
    int w2 = w - 2240;
    sidx = w2 >> 5; qt = w2 & 31;
    Kb = kp + (long)sidx * 51200;
    Vb = vtp + (long)sidx * 51200;
    int b = sidx >> 2, h = sidx & 3;
    Qb = qp + (long)b * 4000 * 256 + h * 64; qstr = 256;
    Ob = cat + (long)b * 4000 * 512 + 256 + h * 64; ostr = 512;
    nq = 4000;
  }

  int qrow = qt * 128 + wv * 16 + l15;
  int qrc = min(qrow, nq - 1);
  short8 q0 = *(const short8*)(Qb + (long)qrc * qstr + lg * 8);
  short8 q1 = *(const short8*)(Qb + (long)qrc * qstr + 32 + lg * 8);

  float m = NEGBIG, ls = 0.f;
  f32x4 oacc[4] = {};

  // staging: each wave stages 8 K-rows (1KB) + 8 V^T-rows (1KB): 2 gloads/wave/tile
  const int srl = lane >> 3;                        // 0..7 (row within wave chunk)
  const int swb = (((lane & 7) ^ srl) << 4);        // pre-swizzled 16B block in 128B row

#define FSTAGE(buf, t)                                                          \
  {                                                                             \
    int base = (t) * 64;                                                        \
    gload16(Kb + (long)min(base + wv * 8 + srl, 799) * 64 + (swb >> 1),         \
            &lK[buf][wv * 512]);                                                \
    gload16(Vb + (long)(wv * 8 + srl) * 800 + min(base + (swb >> 1), 792),      \
            &lV[buf][wv * 512]);                                                \
  }

  // one KV tile: MASKED=1 only on the final (partial) tile
#define FTILE(t, MASKED)                                                        \
  {                                                                             \
    /* S^T = K x Q (exp2 domain) */                                             \
    f32x4 st[4];                                                                \
    __builtin_amdgcn_s_setprio(1);                                              \
    _Pragma("unroll")                                                           \
    for (int ns = 0; ns < 4; ++ns) {                                            \
      int row = ns * 16 + l15;                                                  \
      short8 k0 = *(const short8*)((char*)lK[(t) & 1] + row * 128 +             \
                                   ((lg * 16) ^ ((l15 & 7) << 4)));             \
      short8 k1 = *(const short8*)((char*)lK[(t) & 1] + row * 128 +             \
                                   ((64 + lg * 16) ^ ((l15 & 7) << 4)));        \
      f32x4 z = {};                                                             \
      z = MFMA16(k0, q0, z);                                                    \
      z = MFMA16(k1, q1, z);                                                    \
      st[ns] = z;                                                               \
    }                                                                           \
    __builtin_amdgcn_s_setprio(0);                                              \
    /* online softmax (q = l15), defer-max THR=8 */                             \
    float pv[16];                                                               \
    float pmax = NEGBIG;                                                        \
    _Pragma("unroll")                                                           \
    for (int ns = 0; ns < 4; ++ns)                                              \
      _Pragma("unroll")                                                         \
      for (int r = 0; r < 4; ++r) {                                             \
        float v = st[ns][r];                                                    \
        if (MASKED) {                                                           \
          int tok = (t) * 64 + lg * 4 + ns * 16 + r;                            \
          v = (tok < 800) ? v : NEGBIG;                                         \
        }                                                                       \
        pv[ns * 4 + r] = v;                                                     \
        pmax = fmaxf(pmax, v);                                                  \
      }                                                                         \
    pmax = fmaxf(pmax, __shfl_xor(pmax, 16));                                   \
    pmax = fmaxf(pmax, __shfl_xor(pmax, 32));                                   \
    if (__any(pmax > m + 8.0f)) {                                               \
      float mn = fmaxf(m, pmax);                                                \
      float sc = exp2f(m - mn);                                                 \
      ls *= sc;                                                                 \
      _Pragma("unroll")                                                         \
      for (int n = 0; n < 4; ++n) oacc[n] *= sc;                                \
      m = mn;                                                                   \
    }                                                                           \
    float lsl = 0.f;                                                            \
    _Pragma("unroll")                                                           \
    for (int i = 0; i < 16; ++i) { float e = exp2f(pv[i] - m); pv[i] = e; lsl += e; } \
    ls += lsl;                                                                  \
    /* pack P -> lP (wave-private), b64 swizzled writes */                      \
    _Pragma("unroll")                                                           \
    for (int ns = 0; ns < 4; ++ns) {                                            \
      uint2 val;                                                                \
      val.x = cvtpk(pv[ns * 4 + 0], pv[ns * 4 + 1]);                            \
      val.y = cvtpk(pv[ns * 4 + 2], pv[ns * 4 + 3]);                            \
      *(uint2*)((char*)(&lP[wv][0]) + l15 * 128 +                               \
                ((ns * 32 + lg * 8) ^ ((l15 & 7) << 4))) = val;                 \
    }                                                                           \
    asm volatile("" ::: "memory");                                              \
    /* O^T += V^T x P^T */                                                      \
    __builtin_amdgcn_s_setprio(1);                                              \
    _Pragma("unroll")                                                           \
    for (int half = 0; half < 2; ++half) {                                      \
      short8 pf = *(const short8*)((char*)(&lP[wv][0]) + l15 * 128 +            \
                                   ((half * 64 + lg * 16) ^ ((l15 & 7) << 4))); \
      _Pragma("unroll")                                                         \
      for (int ns2 = 0; ns2 < 4; ++ns2) {                                       \
        int row = ns2 * 16 + l15;                                               \
        short8 vf = *(const short8*)((char*)lV[(t) & 1] + row * 128 +           \
                                     ((half * 64 + lg * 16) ^ ((l15 & 7) << 4))); \
        oacc[ns2] = MFMA16(vf, pf, oacc[ns2]);                                  \
      }                                                                         \
    }                                                                           \
    __builtin_amdgcn_s_setprio(0);                                              \
  }

  const int NT = 13;            // ceil(800/64); tiles 0..11 full, tile 12 has 32 toks
  FSTAGE(0, 0);
  FSTAGE(1, 1);
  for (int t = 0; t < NT - 1; ++t) {     // fast path: no masking
    WAITVM(2);
    BARRIER();
    FTILE(t, 0);
    BARRIER();
    if (t + 2 < NT) FSTAGE(t & 1, t + 2);
  }
  {                                      // final masked tile
    WAITVM(0);
    BARRIER();
    FTILE(12, 1);
    BARRIER();
  }
#undef FSTAGE
#undef FTILE

  // ---- finalize ----
  ls += __shfl_xor(ls, 16);
  ls += __shfl_xor(ls, 32);
  float inv = 1.0f / ls;

  // transpose O through LDS (reuse lK[0..1] as one 16KB [128 q][64 d] swizzled tile)
  {
    int qrl = wv * 16 + l15;
#pragma unroll
    for (int ns2 = 0; ns2 < 4; ++ns2) {
      uint2 val;
      val.x = (unsigned)f2bf(oacc[ns2][0] * inv) | ((unsigned)f2bf(oacc[ns2][1] * inv) << 16);
      val.y = (unsigned)f2bf(oacc[ns2][2] * inv) | ((unsigned)f2bf(oacc[ns2][3] * inv) << 16);
      *(uint2*)((char*)lK + qrl * 128 + ((ns2 * 32 + lg * 8) ^ ((l15 & 7) << 4))) = val;
    }
  }
  __syncthreads();
#pragma unroll
  for (int p = 0; p < 2; ++p) {
    int o = (p * 512 + tid) * 16;
    int row = o >> 7, colb = o & 127;
    int qg2 = qt * 128 + row;
    if (qg2 < nq) {
      float4 v = *(const float4*)((char*)lK + (o & ~127) + (colb ^ ((row & 7) << 4)));
      *(float4*)(Ob + (long)qg2 * ostr + (colb >> 1)) = v;
    }
  }
}

// ---------- launch ----------
extern "C" void kernel_launch(void* const* d_in, const int* in_sizes, int n_in,
                              void* d_out, int out_size, void* d_ws, size_t ws_size,
                              hipStream_t stream) {
  const float* x      = (const float*)d_in[0];
  const float* gqkv_w = (const float*)d_in[1];
  const float* gqkv_b = (const float*)d_in[2];
  const float* pq_w   = (const float*)d_in[3];
  const float* pq_b   = (const float*)d_in[4];
  const float* pkv_w  = (const float*)d_in[5];
  const float* pkv_b  = (const float*)d_in[6];
  const float* conv_w = (const float*)d_in[7];
  const float* conv_b = (const float*)d_in[8];
  const float* ln_g   = (const float*)d_in[9];
  const float* ln_b   = (const float*)d_in[10];
  const float* proj_w = (const float*)d_in[11];
  const float* proj_b = (const float*)d_in[12];

  char* ws = (char*)d_ws;
  unsigned short* xbf  = (unsigned short*)(ws + 0);           // aliased by cat
  unsigned short* cat  = xbf;
  unsigned short* qg   = (unsigned short*)(ws + 65536000);    // grid Q gathered (*SM2)
  unsigned short* kg   = (unsigned short*)(ws + 98304000);    // grid K gathered
  unsigned short* vg   = (unsigned short*)(ws + 131072000);   // grid V gathered
  unsigned short* qp   = (unsigned short*)(ws + 163840000);   // pool Q (*SM2)
  unsigned short* pr   = (unsigned short*)(ws + 196608000);   // pooled (dead -> vtg)
  float*          cvt  = (float*)        (ws + 209715200);    // conv out (dead -> vtg)
  unsigned short* vtg  = (unsigned short*)(ws + 196608000);   // grid V^T (alias pr+cvt)
  unsigned short* p2   = (unsigned short*)(ws + 235929600);   // ln+gelu (dead -> vtp)
  unsigned short* vtp  = (unsigned short*)(ws + 235929600);   // pool V^T (alias p2)
  unsigned short* kp   = (unsigned short*)(ws + 249036800);   // pool K gathered
  unsigned short* vp   = (unsigned short*)(ws + 255590400);   // pool V gathered
  unsigned short* wtg  = (unsigned short*)(ws + 262144000);   // [768][512]
  unsigned short* wtkv = (unsigned short*)(ws + 263192576);
  unsigned short* wtc  = (unsigned short*)(ws + 263716864);
  unsigned short* wtp  = (unsigned short*)(ws + 264241152);

  // prep
  cast_f32_bf16<<<32000, 256, 0, stream>>>(x, xbf, 64000L * 512);
  wtrans5<<<dim3(1536, 5), 256, 0, stream>>>(gqkv_w, pq_w, pkv_w, conv_w, proj_w, wtg);
  pool_mean<<<12800, 256, 0, stream>>>(xbf, pr);

  // pool branch (small GEMMs keep the 128^2 kernel)
  gemm_bf16<<<dim3(4, 100), 256, 0, stream>>>(pr, wtc, conv_b, cvt, nullptr,
                                              12800, 512, 512, 1);
  ln_gelu<<<12800, 256, 0, stream>>>(cvt, ln_g, ln_b, p2);
  gemm_bf16<<<dim3(4, 100), 256, 0, stream>>>(p2, wtkv, pkv_b, kp, vp,
                                              12800, 512, 512, 3);

  // merged gqkv + pool-Q projection (B = wtg||wtq contiguous, N=1024) — 256^2 4-phase
  gemm256<<<dim3(4, 250), 512, 0, stream>>>(xbf, wtg, gqkv_b, pq_b,
                                            qg, kg, vg, qp,
                                            64000, 1024, 512, 2);

  // V transposes (pr/cvt and p2 dead by now)
  vtrans<<<dim3(13, 320), 256, 0, stream>>>(vg, vtg);
  vtrans<<<dim3(13, 64), 256, 0, stream>>>(vp, vtp);

  // merged attentions -> cat (xbf dead after merged GEMM): 2240 grid + 2048 pool
  flash_v6<<<4288, 512, 0, stream>>>(qg, kg, vtg, qp, kp, vtp, cat);

  // output projection (fp32 out) — 256^2 4-phase
  gemm256<<<dim3(2, 250), 512, 0, stream>>>(cat, wtp, proj_b, nullptr,
                                            d_out, nullptr, nullptr, nullptr,
                                            64000, 512, 512, 1);
}